// Round 11
// baseline (326.362 us; speedup 1.0000x reference)
//
#include <hip/hip_runtime.h>
#include <hip/hip_bf16.h>
#include <cmath>

#define Bb 8
#define Tt 4096
#define Dd 512
#define Hh 512
#define Mm (Bb*Tt)

// GEMM tiling (A-only LDS staging, W from L1/L2)
#define BM 128
#define BN 64
#define BK 64
#define BUFB 16384              // bytes per LDS buffer: BM*BK*2 (A only)

// scan chunking
#define NCHUNK 64
#define CLEN (Tt/NCHUNK)   // 64

typedef unsigned short u16;
typedef unsigned int   u32;
typedef __attribute__((ext_vector_type(8))) short bf16x8;
typedef __attribute__((ext_vector_type(4))) float f32x4;
typedef __attribute__((address_space(3))) char lds_char;

__device__ __forceinline__ u16 f2bf(float f) {
    u32 u = __float_as_uint(f);
    u += 0x7fffu + ((u >> 16) & 1u);   // RNE
    return (u16)(u >> 16);
}
__device__ __forceinline__ float bf2f_lo(u32 p) { return __uint_as_float(p << 16); }
__device__ __forceinline__ float bf2f_hi(u32 p) { return __uint_as_float(p & 0xffff0000u); }

__device__ __forceinline__ void gl2lds16(const void* g, lds_char* l) {
    __builtin_amdgcn_global_load_lds(
        (const __attribute__((address_space(1))) u32*)g,
        (__attribute__((address_space(3))) u32*)l, 16, 0, 0);
}

// ---------------- kernel 0: fp32 -> bf16 convert ----------------
// x -> xb (row-major bf16). W_f/W_i/W_h -> Wt fragment-major:
// element (g, n, k) at byte (g*64 + k/8)*8192 + n*16 + (k%8)*2,
// i.e. Wt[g][kq][n][8] — one wave's B-fragment read is fully coalesced.
__global__ void cvt_all(const float* __restrict__ x,
                        const float* __restrict__ wf, const float* __restrict__ wi,
                        const float* __restrict__ wh,
                        u16* __restrict__ xb, char* __restrict__ wt, int n8x) {
    int i = blockIdx.x * blockDim.x + threadIdx.x;
    const float* in; int idx;
    uint4* dst;
    if (i < n8x) {
        in = x; idx = i;
        dst = reinterpret_cast<uint4*>(xb) + idx;
    } else {
        int j = i - n8x;              // 0 .. 3*32768-1
        int g = j >> 15;
        idx = j & 32767;
        in = (g == 0) ? wf : (g == 1) ? wi : wh;
        int n  = idx >> 6;            // row (output col) 0..511
        int kq = idx & 63;            // k/8 block 0..63
        dst = reinterpret_cast<uint4*>(wt + ((size_t)((g << 6) + kq) << 13) + ((size_t)n << 4));
    }
    float4 a = reinterpret_cast<const float4*>(in)[idx*2];
    float4 b = reinterpret_cast<const float4*>(in)[idx*2+1];
    union { u16 u[8]; uint4 v; } r;
    r.u[0]=f2bf(a.x); r.u[1]=f2bf(a.y); r.u[2]=f2bf(a.z); r.u[3]=f2bf(a.w);
    r.u[4]=f2bf(b.x); r.u[5]=f2bf(b.y); r.u[6]=f2bf(b.z); r.u[7]=f2bf(b.w);
    *dst = r.v;
}

// ---------------- kernel 1: fused 3-gate GEMM + gate math + chunk composites ----------------
// A-only LDS staging (16 KB/buf, 128B rows, XOR swizzle ((row&7)<<4) on global
// source + ds_read addr, conflict-free). W fragments load straight from
// L1/L2-resident Wt to VGPRs each k-step (coalesced fragment-major layout).
// KEY CHANGE vs r10: __launch_bounds__(256,4) -> 4 blocks/CU (128 KB LDS,
// VGPR<=128). Four independent barrier groups per CU hide the W-load latency
// that r10 exposed at 2 blocks/CU (m114 cross-block overlap). This escapes the
// 36% LDS-read-BW ceiling of the W-in-LDS design (128 B/cyc vs 351 B/cyc demand).
__global__ __launch_bounds__(256, 4)
void gate_gemm(const u16* __restrict__ xb,      // [Mm][Dd] bf16
               const char* __restrict__ wt,     // Wt[g][kq][n][8] bf16
               const float* __restrict__ b_f, const float* __restrict__ b_i,
               const float* __restrict__ b_h,
               u32* __restrict__ FV,            // packed bf16 f | v<<16
               float* __restrict__ Fc, float* __restrict__ Vc)
{
    __shared__ __align__(128) u16 sbuf[2 * BUFB / 2];   // 32 KB

    const int tid  = threadIdx.x;
    const int lane = tid & 63;
    const int w    = tid >> 6;
    const int wm   = w >> 1;    // 0..1
    const int wn   = w & 1;     // 0..1

    // XCD-bijective swizzle: consecutive-n blocks stay on one XCD -> A panel L2-hot
    const int bid = blockIdx.x;
    const int lg  = (bid >> 3) + (bid & 7) * ((int)gridDim.x >> 3);
    const int m0  = (lg >> 3) * BM;
    const int n0  = (lg & 7) * BN;

    // ---- A staging addresses (pre-swizzled global source, linear LDS dest) ----
    const int lrow = lane >> 3;                       // row within 8-row group
    const int scb  = ((lane & 7) * 16) ^ (lrow << 4); // swizzled col-byte
    lds_char* Lb = (lds_char*)&sbuf[0];

    const char* ap[4]; int aOff[4];
    #pragma unroll
    for (int s = 0; s < 4; ++s) {
        ap[s] = (const char*)xb + ((size_t)(m0 + w*32 + s*8 + lrow) << 10) + scb;
        aOff[s] = (w*4 + s) * 1024;
    }

    // ---- W fragment addressing (global, uniform base + per-lane offset) ----
    // frag (g, ni, tile t, kstep s): kq = t*8 + s*4 + (lane>>4), n = n0+wn*32+ni*16+(lane&15)
    const int lanebyte = ((lane >> 4) << 13) | ((lane & 15) << 4);
    const char* wbase = wt + ((size_t)(n0 + wn*32) << 4) + lanebyte;

    // ---- A fragment read offsets (swizzled) ----
    const int arow  = wm*64 + (lane & 15);
    const int sw    = (lane & 7) << 4;
    int acol[2];
    #pragma unroll
    for (int s = 0; s < 2; ++s)
        acol[s] = ((s*64) | ((lane >> 4) * 16)) ^ sw;

    f32x4 acc[3][4][2];
    #pragma unroll
    for (int g = 0; g < 3; ++g)
        #pragma unroll
        for (int mi = 0; mi < 4; ++mi)
            #pragma unroll
            for (int ni = 0; ni < 2; ++ni)
                acc[g][mi][ni] = (f32x4){0.f,0.f,0.f,0.f};

    auto STAGE = [&](int bo) {           // 4 global_load_lds (A only), advance ptrs
        #pragma unroll
        for (int s = 0; s < 4; ++s) { gl2lds16(ap[s], Lb + bo + aOff[s]); ap[s] += 2*BK; }
    };
    auto COMPUTE = [&](int bo, int t) {
        const char* sA = (const char*)&sbuf[0] + bo;
        #pragma unroll
        for (int s = 0; s < 2; ++s) {
            bf16x8 a[4];
            #pragma unroll
            for (int mi = 0; mi < 4; ++mi)
                a[mi] = *(const bf16x8*)(sA + ((arow + mi*16) << 7) + acol[s]);
            #pragma unroll
            for (int g = 0; g < 3; ++g) {
                const char* pg = wbase + ((size_t)((g << 6) + (t << 3) + (s << 2)) << 13);
                bf16x8 w0 = *(const bf16x8*)(pg);
                bf16x8 w1 = *(const bf16x8*)(pg + 256);   // ni=1: +16 cols * 16B
                #pragma unroll
                for (int mi = 0; mi < 4; ++mi) {
                    acc[g][mi][0] = __builtin_amdgcn_mfma_f32_16x16x32_bf16(a[mi], w0, acc[g][mi][0], 0,0,0);
                    acc[g][mi][1] = __builtin_amdgcn_mfma_f32_16x16x32_bf16(a[mi], w1, acc[g][mi][1], 0,0,0);
                }
            }
        }
    };

    // prologue: tile 0 -> buf0
    STAGE(0);
    __syncthreads();

    // steady state: 8 K-tiles total, manually 2-unrolled for static buffer select
    #pragma unroll 1
    for (int i = 0; i < 3; ++i) {
        STAGE(BUFB); COMPUTE(0, 2*i);        __syncthreads();
        STAGE(0);    COMPUTE(BUFB, 2*i + 1); __syncthreads();
    }
    STAGE(BUFB); COMPUTE(0, 6); __syncthreads();
    COMPUTE(BUFB, 7);

    // ---- epilogue: gates + FV store + fused chunk composites (unchanged) ----
    // fg = I/(F+I), ig = F/(F+I), F=1+e^-zf, I=1+e^-zi
    const int col = lane & 15;
    const int lg4 = lane >> 4;
    const int rb  = lg4 * 4;
    const int gch = (m0 >> 6) + wm;        // global chunk index == b*NCHUNK+ch

    #pragma unroll
    for (int ni = 0; ni < 2; ++ni) {
        const int h = n0 + wn*32 + ni*16 + col;
        const float bfv = b_f[h], biv = b_i[h], bhv = b_h[h];
        float Fr = 1.0f, Vr = 0.0f;        // running chunk composite
        #pragma unroll
        for (int mi = 0; mi < 4; ++mi) {
            float F4 = 1.0f, V4 = 0.0f;    // local 4-row run composite
            #pragma unroll
            for (int r = 0; r < 4; ++r) {
                const int m = m0 + wm*64 + mi*16 + rb + r;
                float zf = acc[0][mi][ni][r] + bfv;
                float zi = acc[1][mi][ni][r] + biv;
                float zh = acc[2][mi][ni][r] + bhv;
                float ef = __expf(fminf(-zf, 60.0f));
                float ei = __expf(fminf(-zi, 60.0f));
                float rr = __builtin_amdgcn_rcpf(2.0f + ef + ei);
                float fg = (1.0f + ei) * rr;
                float ig = (1.0f + ef) * rr;
                float eh = __expf(fminf(-zh, 60.0f));
                float gv = (zh >= 0.0f) ? (zh + 0.5f) : __builtin_amdgcn_rcpf(1.0f + eh);
                float vv = ig * gv;
                __hip_bfloat16 blo = __float2bfloat16(fg);
                __hip_bfloat16 bhi = __float2bfloat16(vv);
                u32 pk = (u32)*reinterpret_cast<u16*>(&blo) |
                         ((u32)*reinterpret_cast<u16*>(&bhi) << 16);
                FV[(size_t)m * Hh + h] = pk;
                // rounded values so composites match the apply kernel's replay
                float f_ = bf2f_lo(pk), v_ = bf2f_hi(pk);
                V4 = fmaf(f_, V4, v_);
                F4 *= f_;
            }
            // ordered butterfly compose across lane bits 4 and 5
            {
                float Fp = __shfl_xor(F4, 16), Vp = __shfl_xor(V4, 16);
                float Fl = (lane & 16) ? Fp : F4, Vl = (lane & 16) ? Vp : V4;
                float Fh = (lane & 16) ? F4 : Fp, Vh = (lane & 16) ? V4 : Vp;
                F4 = Fh * Fl; V4 = fmaf(Fh, Vl, Vh);
                Fp = __shfl_xor(F4, 32); Vp = __shfl_xor(V4, 32);
                Fl = (lane & 32) ? Fp : F4; Vl = (lane & 32) ? Vp : V4;
                Fh = (lane & 32) ? F4 : Fp; Vh = (lane & 32) ? V4 : Vp;
                F4 = Fh * Fl; V4 = fmaf(Fh, Vl, Vh);
            }
            Vr = fmaf(F4, Vr, V4);
            Fr = F4 * Fr;
        }
        if (lg4 == 0) {
            Fc[(size_t)gch * Hh + h] = Fr;
            Vc[(size_t)gch * Hh + h] = Vr;
        }
    }
}

// ---------------- scan apply: redundant per-block prefix + chunk replay ----------------
__global__ void scan_apply(const u32* __restrict__ FV,
                           const float* __restrict__ h0,
                           const float2* __restrict__ Fc2, const float2* __restrict__ Vc2,
                           float2* __restrict__ out2)
{
    const int t2 = threadIdx.x;               // h-pair 0..255
    const int b = blockIdx.x, ch = blockIdx.y;

    // g(h_0)
    float2 x0 = reinterpret_cast<const float2*>(h0)[b * (Hh/2) + t2];
    float2 hh;
    hh.x = (x0.x >= 0.f) ? (x0.x + 0.5f) : __builtin_amdgcn_rcpf(1.f + __expf(-x0.x));
    hh.y = (x0.y >= 0.f) ? (x0.y + 0.5f) : __builtin_amdgcn_rcpf(1.f + __expf(-x0.y));

    // prefix over chunk composites [0, ch)  (bitwise-identical sequential order)
    #pragma unroll 4
    for (int k = 0; k < ch; ++k) {
        int ci = (b * NCHUNK + k) * (Hh/2) + t2;
        float2 F = Fc2[ci];
        float2 V = Vc2[ci];
        hh.x = fmaf(F.x, hh.x, V.x);
        hh.y = fmaf(F.y, hh.y, V.y);
    }

    // replay this chunk
    const uint2* p = (const uint2*)FV;
    size_t base = ((size_t)b * Tt + (size_t)ch * CLEN) * (Hh/2) + t2;
    #pragma unroll 4
    for (int t = 0; t < CLEN; ++t) {
        size_t idx = base + (size_t)t * (Hh/2);
        uint2 fv = p[idx];
        hh.x = fmaf(bf2f_lo(fv.x), hh.x, bf2f_hi(fv.x));
        hh.y = fmaf(bf2f_lo(fv.y), hh.y, bf2f_hi(fv.y));
        out2[idx] = hh;
    }
}

extern "C" void kernel_launch(void* const* d_in, const int* in_sizes, int n_in,
                              void* d_out, int out_size, void* d_ws, size_t ws_size,
                              hipStream_t stream) {
    const float* x   = (const float*)d_in[0];
    const float* h0  = (const float*)d_in[1];
    const float* W_f = (const float*)d_in[2];
    const float* b_f = (const float*)d_in[3];
    const float* W_i = (const float*)d_in[4];
    const float* b_i = (const float*)d_in[5];
    const float* W_h = (const float*)d_in[6];
    const float* b_h = (const float*)d_in[7];
    float* out = (float*)d_out;

    // workspace layout
    char* ws = (char*)d_ws;
    u16*  xb = (u16*)ws;                                         // 32 MB
    char* wt = ws + (size_t)Mm * Dd * 2;                         // 1.5 MB (Wt)
    u32*  FV = (u32*)(ws + (size_t)Mm * Dd * 2 + (size_t)3 * Hh * Dd * 2); // 64 MB
    float* Fc = (float*)(FV + (size_t)Mm * Hh);                  // 1 MB
    float* Vc = Fc + (size_t)Bb * NCHUNK * Hh;                   // 1 MB

    // 0) converts (x + 3 W's in one launch; W transposed to fragment-major)
    {
        int n8x = Mm * Dd / 8;                 // 2,097,152
        int total = n8x + 3 * (Hh * Dd / 8);   // + 98,304
        cvt_all<<<total / 256, 256, 0, stream>>>(x, W_f, W_i, W_h, xb, wt, n8x);
    }

    // 1) fused 3-gate GEMM + gate math + chunk composites
    gate_gemm<<<(Mm / BM) * (Hh / BN), 256, 0, stream>>>(xb, wt, b_f, b_i, b_h, FV, Fc, Vc);

    // 2) fused prefix + apply
    {
        dim3 g1(Bb, NCHUNK);
        scan_apply<<<g1, 256, 0, stream>>>(FV, h0, (const float2*)Fc, (const float2*)Vc, (float2*)out);
    }
}

// Round 12
// 106.308 us; speedup vs baseline: 3.0700x; 3.0700x over previous
//
#include <hip/hip_runtime.h>
#include <hip/hip_bf16.h>
#include <cmath>

#define Bb 8
#define Tt 4096
#define Dd 512
#define Hh 512
#define Mm (Bb*Tt)

// GEMM tiling (round-3 verified config)
#define BM 128
#define BN 64
#define BK 64
#define BUFB 40960              // bytes per LDS buffer: (BM + 3*BN)*BK*2

// scan chunking
#define NCHUNK 64
#define CLEN (Tt/NCHUNK)   // 64

typedef unsigned short u16;
typedef unsigned int   u32;
typedef __attribute__((ext_vector_type(8))) short bf16x8;
typedef __attribute__((ext_vector_type(4))) float f32x4;
typedef __attribute__((address_space(3))) char lds_char;

__device__ __forceinline__ u16 f2bf(float f) {
    u32 u = __float_as_uint(f);
    u += 0x7fffu + ((u >> 16) & 1u);   // RNE
    return (u16)(u >> 16);
}
__device__ __forceinline__ float bf2f_lo(u32 p) { return __uint_as_float(p << 16); }
__device__ __forceinline__ float bf2f_hi(u32 p) { return __uint_as_float(p & 0xffff0000u); }

__device__ __forceinline__ void gl2lds16(const void* g, lds_char* l) {
    __builtin_amdgcn_global_load_lds(
        (const __attribute__((address_space(1))) u32*)g,
        (__attribute__((address_space(3))) u32*)l, 16, 0, 0);
}

// ---------------- kernel 0: fp32 -> bf16 convert (x and the 3 W's, one launch) ----------------
__global__ void cvt_all(const float* __restrict__ x,
                        const float* __restrict__ wf, const float* __restrict__ wi,
                        const float* __restrict__ wh,
                        u16* __restrict__ xb, u16* __restrict__ wbuf, int n8x) {
    int i = blockIdx.x * blockDim.x + threadIdx.x;
    const float* in; u16* o; int idx;
    if (i < n8x) { in = x; o = xb; idx = i; }
    else {
        int j = i - n8x;              // 0 .. 3*32768-1
        int g = j >> 15;
        idx = j & 32767;
        in = (g == 0) ? wf : (g == 1) ? wi : wh;
        o = wbuf + (size_t)g * Hh * Dd;
    }
    float4 a = reinterpret_cast<const float4*>(in)[idx*2];
    float4 b = reinterpret_cast<const float4*>(in)[idx*2+1];
    union { u16 u[8]; uint4 v; } r;
    r.u[0]=f2bf(a.x); r.u[1]=f2bf(a.y); r.u[2]=f2bf(a.z); r.u[3]=f2bf(a.w);
    r.u[4]=f2bf(b.x); r.u[5]=f2bf(b.y); r.u[6]=f2bf(b.z); r.u[7]=f2bf(b.w);
    reinterpret_cast<uint4*>(o)[idx] = r.v;
}

// ---------------- kernel 1: fused 3-gate GEMM + gate math + chunk composites ----------------
// EXACT round-3 GEMM core (measured best): LDS per buffer A[128][64] bf16 (16 KB)
// + W[3][64][64] (24 KB), 128B rows, XOR swizzle byte ^= ((row&7)<<4) on GLOBAL
// source and ds_read address. Plain 2-phase dbuf with __syncthreads only.
// Structure ceiling is LDS-read BW: 160KB/CU-round / 128 B/cyc = 1280 cyc vs
// 466 cyc MFMA -> ~36% MfmaUtil. Six attack variants (r4-r7, r10, r11) all
// regressed; this is the measured-best configuration.
__global__ __launch_bounds__(256, 2)
void gate_gemm(const u16* __restrict__ xb,      // [Mm][Dd] bf16
               const u16* __restrict__ wb,      // [3][Hh][Dd] bf16
               const float* __restrict__ b_f, const float* __restrict__ b_i,
               const float* __restrict__ b_h,
               u32* __restrict__ FV,            // packed bf16 f | v<<16
               float* __restrict__ Fc, float* __restrict__ Vc)
{
    __shared__ __align__(128) u16 sbuf[2 * BUFB / 2];   // 80 KB

    const int tid  = threadIdx.x;
    const int lane = tid & 63;
    const int w    = tid >> 6;
    const int wm   = w >> 1;    // 0..1
    const int wn   = w & 1;     // 0..1

    // XCD-bijective swizzle: consecutive-n blocks stay on one XCD -> A panel L2-hot
    const int bid = blockIdx.x;
    const int lg  = (bid >> 3) + (bid & 7) * ((int)gridDim.x >> 3);
    const int m0  = (lg >> 3) * BM;
    const int n0  = (lg & 7) * BN;

    // ---- staging addresses (pre-swizzled global source, linear LDS dest) ----
    const int lrow = lane >> 3;                       // row within 8-row group
    const int scb  = ((lane & 7) * 16) ^ (lrow << 4); // swizzled col-byte
    lds_char* Lb = (lds_char*)&sbuf[0];

    const char* ap[4]; int aOff[4];
    #pragma unroll
    for (int s = 0; s < 4; ++s) {
        ap[s] = (const char*)xb + ((size_t)(m0 + w*32 + s*8 + lrow) << 10) + scb;
        aOff[s] = (w*4 + s) * 1024;
    }
    const char* wp[6]; int wOff[6];
    #pragma unroll
    for (int s = 0; s < 6; ++s) {
        int jj = w*6 + s;                 // 0..23 over [3][64] rows /8
        int g  = jj >> 3;
        int hg = (jj & 7) * 8 + lrow;
        wp[s] = (const char*)wb + ((size_t)(g*Hh + n0 + hg) << 10) + scb;
        wOff[s] = 16384 + jj * 1024;
    }

    // ---- fragment read offsets (swizzled) ----
    const int arow  = wm*64 + (lane & 15);
    const int wrow  = wn*32 + (lane & 15);
    const int sw    = (lane & 7) << 4;
    int acol[2];
    #pragma unroll
    for (int s = 0; s < 2; ++s)
        acol[s] = ((s*64) | ((lane >> 4) * 16)) ^ sw;

    f32x4 acc[3][4][2];
    #pragma unroll
    for (int g = 0; g < 3; ++g)
        #pragma unroll
        for (int mi = 0; mi < 4; ++mi)
            #pragma unroll
            for (int ni = 0; ni < 2; ++ni)
                acc[g][mi][ni] = (f32x4){0.f,0.f,0.f,0.f};

    auto STAGE = [&](int bo) {           // issue 10 global_load_lds, advance ptrs
        #pragma unroll
        for (int s = 0; s < 4; ++s) { gl2lds16(ap[s], Lb + bo + aOff[s]); ap[s] += 2*BK; }
        #pragma unroll
        for (int s = 0; s < 6; ++s) { gl2lds16(wp[s], Lb + bo + wOff[s]); wp[s] += 2*BK; }
    };
    auto COMPUTE = [&](int bo) {
        const char* sA = (const char*)&sbuf[0] + bo;
        #pragma unroll
        for (int s = 0; s < 2; ++s) {
            bf16x8 a[4];
            #pragma unroll
            for (int mi = 0; mi < 4; ++mi)
                a[mi] = *(const bf16x8*)(sA + ((arow + mi*16) << 7) + acol[s]);
            #pragma unroll
            for (int g = 0; g < 3; ++g) {
                bf16x8 w0 = *(const bf16x8*)(sA + 16384 + g*8192 + (wrow << 7) + acol[s]);
                bf16x8 w1 = *(const bf16x8*)(sA + 16384 + g*8192 + ((wrow + 16) << 7) + acol[s]);
                #pragma unroll
                for (int mi = 0; mi < 4; ++mi) {
                    acc[g][mi][0] = __builtin_amdgcn_mfma_f32_16x16x32_bf16(a[mi], w0, acc[g][mi][0], 0,0,0);
                    acc[g][mi][1] = __builtin_amdgcn_mfma_f32_16x16x32_bf16(a[mi], w1, acc[g][mi][1], 0,0,0);
                }
            }
        }
    };

    // prologue: tile 0 -> buf0
    STAGE(0);
    __syncthreads();

    // steady state: 8 K-tiles total, manually 2-unrolled for static buffer select
    #pragma unroll 1
    for (int i = 0; i < 3; ++i) {
        STAGE(BUFB); COMPUTE(0);    __syncthreads();
        STAGE(0);    COMPUTE(BUFB); __syncthreads();
    }
    STAGE(BUFB); COMPUTE(0); __syncthreads();
    COMPUTE(BUFB);

    // ---- epilogue: gates + FV store + fused chunk composites ----
    // fg = I/(F+I), ig = F/(F+I), F=1+e^-zf, I=1+e^-zi
    const int col = lane & 15;
    const int lg4 = lane >> 4;
    const int rb  = lg4 * 4;
    const int gch = (m0 >> 6) + wm;        // global chunk index == b*NCHUNK+ch

    #pragma unroll
    for (int ni = 0; ni < 2; ++ni) {
        const int h = n0 + wn*32 + ni*16 + col;
        const float bfv = b_f[h], biv = b_i[h], bhv = b_h[h];
        float Fr = 1.0f, Vr = 0.0f;        // running chunk composite
        #pragma unroll
        for (int mi = 0; mi < 4; ++mi) {
            float F4 = 1.0f, V4 = 0.0f;    // local 4-row run composite
            #pragma unroll
            for (int r = 0; r < 4; ++r) {
                const int m = m0 + wm*64 + mi*16 + rb + r;
                float zf = acc[0][mi][ni][r] + bfv;
                float zi = acc[1][mi][ni][r] + biv;
                float zh = acc[2][mi][ni][r] + bhv;
                float ef = __expf(fminf(-zf, 60.0f));
                float ei = __expf(fminf(-zi, 60.0f));
                float rr = __builtin_amdgcn_rcpf(2.0f + ef + ei);
                float fg = (1.0f + ei) * rr;
                float ig = (1.0f + ef) * rr;
                float eh = __expf(fminf(-zh, 60.0f));
                float gv = (zh >= 0.0f) ? (zh + 0.5f) : __builtin_amdgcn_rcpf(1.0f + eh);
                float vv = ig * gv;
                __hip_bfloat16 blo = __float2bfloat16(fg);
                __hip_bfloat16 bhi = __float2bfloat16(vv);
                u32 pk = (u32)*reinterpret_cast<u16*>(&blo) |
                         ((u32)*reinterpret_cast<u16*>(&bhi) << 16);
                FV[(size_t)m * Hh + h] = pk;
                // rounded values so composites match the apply kernel's replay
                float f_ = bf2f_lo(pk), v_ = bf2f_hi(pk);
                V4 = fmaf(f_, V4, v_);
                F4 *= f_;
            }
            // ordered butterfly compose across lane bits 4 and 5
            {
                float Fp = __shfl_xor(F4, 16), Vp = __shfl_xor(V4, 16);
                float Fl = (lane & 16) ? Fp : F4, Vl = (lane & 16) ? Vp : V4;
                float Fh = (lane & 16) ? F4 : Fp, Vh = (lane & 16) ? V4 : Vp;
                F4 = Fh * Fl; V4 = fmaf(Fh, Vl, Vh);
                Fp = __shfl_xor(F4, 32); Vp = __shfl_xor(V4, 32);
                Fl = (lane & 32) ? Fp : F4; Vl = (lane & 32) ? Vp : V4;
                Fh = (lane & 32) ? F4 : Fp; Vh = (lane & 32) ? V4 : Vp;
                F4 = Fh * Fl; V4 = fmaf(Fh, Vl, Vh);
            }
            Vr = fmaf(F4, Vr, V4);
            Fr = F4 * Fr;
        }
        if (lg4 == 0) {
            Fc[(size_t)gch * Hh + h] = Fr;
            Vc[(size_t)gch * Hh + h] = Vr;
        }
    }
}

// ---------------- scan apply: redundant per-block prefix + chunk replay ----------------
__global__ void scan_apply(const u32* __restrict__ FV,
                           const float* __restrict__ h0,
                           const float2* __restrict__ Fc2, const float2* __restrict__ Vc2,
                           float2* __restrict__ out2)
{
    const int t2 = threadIdx.x;               // h-pair 0..255
    const int b = blockIdx.x, ch = blockIdx.y;

    // g(h_0)
    float2 x0 = reinterpret_cast<const float2*>(h0)[b * (Hh/2) + t2];
    float2 hh;
    hh.x = (x0.x >= 0.f) ? (x0.x + 0.5f) : __builtin_amdgcn_rcpf(1.f + __expf(-x0.x));
    hh.y = (x0.y >= 0.f) ? (x0.y + 0.5f) : __builtin_amdgcn_rcpf(1.f + __expf(-x0.y));

    // prefix over chunk composites [0, ch)  (bitwise-identical sequential order)
    #pragma unroll 4
    for (int k = 0; k < ch; ++k) {
        int ci = (b * NCHUNK + k) * (Hh/2) + t2;
        float2 F = Fc2[ci];
        float2 V = Vc2[ci];
        hh.x = fmaf(F.x, hh.x, V.x);
        hh.y = fmaf(F.y, hh.y, V.y);
    }

    // replay this chunk
    const uint2* p = (const uint2*)FV;
    size_t base = ((size_t)b * Tt + (size_t)ch * CLEN) * (Hh/2) + t2;
    #pragma unroll 4
    for (int t = 0; t < CLEN; ++t) {
        size_t idx = base + (size_t)t * (Hh/2);
        uint2 fv = p[idx];
        hh.x = fmaf(bf2f_lo(fv.x), hh.x, bf2f_hi(fv.x));
        hh.y = fmaf(bf2f_lo(fv.y), hh.y, bf2f_hi(fv.y));
        out2[idx] = hh;
    }
}

extern "C" void kernel_launch(void* const* d_in, const int* in_sizes, int n_in,
                              void* d_out, int out_size, void* d_ws, size_t ws_size,
                              hipStream_t stream) {
    const float* x   = (const float*)d_in[0];
    const float* h0  = (const float*)d_in[1];
    const float* W_f = (const float*)d_in[2];
    const float* b_f = (const float*)d_in[3];
    const float* W_i = (const float*)d_in[4];
    const float* b_i = (const float*)d_in[5];
    const float* W_h = (const float*)d_in[6];
    const float* b_h = (const float*)d_in[7];
    float* out = (float*)d_out;

    // workspace layout
    char* ws = (char*)d_ws;
    u16*  xb   = (u16*)ws;                                       // 32 MB
    u16*  wbuf = (u16*)(ws + (size_t)Mm * Dd * 2);               // 1.5 MB
    u32*  FV   = (u32*)(ws + (size_t)Mm * Dd * 2 + (size_t)3 * Hh * Dd * 2); // 64 MB
    float* Fc  = (float*)(FV + (size_t)Mm * Hh);                 // 1 MB
    float* Vc  = Fc + (size_t)Bb * NCHUNK * Hh;                  // 1 MB

    // 0) converts (x + 3 W's in one launch)
    {
        int n8x = Mm * Dd / 8;                 // 2,097,152
        int total = n8x + 3 * (Hh * Dd / 8);   // + 98,304 = 2,195,456
        cvt_all<<<total / 256, 256, 0, stream>>>(x, W_f, W_i, W_h, xb, wbuf, n8x);
    }

    // 1) fused 3-gate GEMM + gate math + chunk composites
    gate_gemm<<<(Mm / BM) * (Hh / BN), 256, 0, stream>>>(xb, wbuf, b_f, b_i, b_h, FV, Fc, Vc);

    // 2) fused prefix + apply
    {
        dim3 g1(Bb, NCHUNK);
        scan_apply<<<g1, 256, 0, stream>>>(FV, h0, (const float2*)Fc, (const float2*)Vc, (float2*)out);
    }
}